// Round 2
// baseline (193.665 us; speedup 1.0000x reference)
//
#include <hip/hip_runtime.h>

// NCA step collapsed: y = single 8->8 channel 3x3 circular conv with folded
// kernel K[c][c'][3][3] = sum_f (w1@w0)[c,c',f] * filters[f].
// out = clamp(grid + (noise<0.5) * conv(grid,K), 0, 1)
//
// nca_main: 16x64 tile/block, input channels staged in 2 groups of 4
// (19 KB LDS -> 8 blocks/CU LDS-wise), each thread computes a 2x2 pixel
// patch for all 8 output channels (float2 LDS reads, float2 global IO).

#define B_ 16
#define C_ 8
#define H_ 512
#define W_ 512
#define HID_ 32
#define F_ 5

#define TH 16
#define TW 64
#define GC 4                      // channels per staging group
#define PER_CH ((TH + 2) * (TW + 2))   // 1188
#define GROUP_ELEMS (GC * PER_CH)      // 4752

// ---- prep: fold w1 @ w0 @ filters into K[8][8][9] ----
__global__ void nca_prep(const float* __restrict__ filters,  // [5][3][3]
                         const float* __restrict__ w0,       // [32][40]
                         const float* __restrict__ w1,       // [8][32]
                         float* __restrict__ K)              // [8][8][9]
{
    int idx = blockIdx.x * blockDim.x + threadIdx.x;
    if (idx >= C_ * C_ * 9) return;
    int k  = idx % 9;
    int t  = idx / 9;
    int cp = t % C_;   // input channel
    int c  = t / C_;   // output channel
    float acc = 0.f;
    #pragma unroll
    for (int f = 0; f < F_; ++f) {
        float we = 0.f;
        for (int o = 0; o < HID_; ++o)
            we += w1[c * HID_ + o] * w0[o * (C_ * F_) + cp * F_ + f];
        acc += we * filters[f * 9 + k];
    }
    K[idx] = acc;
}

__global__ __launch_bounds__(256, 5) void nca_main(
    const float* __restrict__ grid,
    const float* __restrict__ noise,
    const float* __restrict__ K,      // [8][8][9]
    float* __restrict__ out)
{
    __shared__ float lds[GC][TH + 2][TW + 2];   // 19,008 B

    const int b   = blockIdx.z;
    const int h0  = blockIdx.y * TH;
    const int w0c = blockIdx.x * TW;
    const int tid = threadIdx.x;
    const int tx  = tid & 31;        // column-pair index (0..31)
    const int ty  = tid >> 5;        // row-pair index (0..7)
    const int lw2 = tx << 1;         // padded base col of 4-col window
    const int R0  = ty << 1;         // padded base row of 4-row window

    float acc[C_][4];
    #pragma unroll
    for (int c = 0; c < C_; ++c)
        #pragma unroll
        for (int p = 0; p < 4; ++p) acc[c][p] = 0.f;

    float cen[GC][4];   // residual centers for group-0 channels

    // one-time staging index decomposition (i = tid)
    const int c_init   = tid / PER_CH;
    const int rem_init = tid - c_init * PER_CH;
    const int r_init   = rem_init / (TW + 2);
    const int col_init = rem_init - r_init * (TW + 2);

    float* lflat = &lds[0][0][0];

    #pragma unroll
    for (int g = 0; g < 2; ++g) {
        // ---- stage 4 channels with circular halo ----
        {
            int c = c_init, r = r_init, col = col_init;
            for (int i = tid; i < GROUP_ELEMS; i += 256) {
                const int gh = (h0 + r - 1) & (H_ - 1);
                const int gw = (w0c + col - 1) & (W_ - 1);
                lflat[i] = grid[(((b << 3) + (g << 2) + c) << 18) + (gh << 9) + gw];
                // advance by 256 = 3 rows + 58 cols
                col += 58; r += 3;
                if (col >= TW + 2) { col -= TW + 2; ++r; }
                if (r >= TH + 2)   { r -= TH + 2; ++c; }
            }
        }
        __syncthreads();

        // ---- accumulate 4 input channels into all 8 output channels ----
        #pragma unroll
        for (int cp = 0; cp < GC; ++cp) {
            float w[4][4];
            #pragma unroll
            for (int r = 0; r < 4; ++r) {
                const float2* p = reinterpret_cast<const float2*>(&lds[cp][R0 + r][lw2]);
                float2 a = p[0];
                float2 bb = p[1];
                w[r][0] = a.x; w[r][1] = a.y; w[r][2] = bb.x; w[r][3] = bb.y;
            }
            if (g == 0) {
                cen[cp][0] = w[1][1]; cen[cp][1] = w[1][2];
                cen[cp][2] = w[2][1]; cen[cp][3] = w[2][2];
            }
            const int gcp = (g << 2) + cp;
            #pragma unroll
            for (int c = 0; c < C_; ++c) {
                const float* __restrict__ kk = K + (c * C_ + gcp) * 9;
                #pragma unroll
                for (int kh = 0; kh < 3; ++kh) {
                    #pragma unroll
                    for (int kw = 0; kw < 3; ++kw) {
                        const float kv = kk[kh * 3 + kw];
                        acc[c][0] += kv * w[0 + kh][0 + kw];
                        acc[c][1] += kv * w[0 + kh][1 + kw];
                        acc[c][2] += kv * w[1 + kh][0 + kw];
                        acc[c][3] += kv * w[1 + kh][1 + kw];
                    }
                }
            }
        }
        if (g == 0) __syncthreads();   // protect LDS before group-1 overwrite
    }
    // note: LDS still holds channels 4..7 for epilogue residual reads

    // ---- epilogue: mask, residual, clamp, float2 store ----
    #pragma unroll
    for (int c = 0; c < C_; ++c) {
        #pragma unroll
        for (int pr = 0; pr < 2; ++pr) {
            const int h  = h0 + R0 + pr;
            const int gi = (((b << 3) + c) << 18) + (h << 9) + (w0c + lw2);
            const float2 nz = *reinterpret_cast<const float2*>(&noise[gi]);
            float g0, g1;
            if (c < GC) {
                g0 = cen[c][pr * 2 + 0];
                g1 = cen[c][pr * 2 + 1];
            } else {
                g0 = lds[c - GC][R0 + 1 + pr][lw2 + 1];
                g1 = lds[c - GC][R0 + 1 + pr][lw2 + 2];
            }
            float o0 = (nz.x < 0.5f) ? (g0 + acc[c][pr * 2 + 0]) : g0;
            float o1 = (nz.y < 0.5f) ? (g1 + acc[c][pr * 2 + 1]) : g1;
            o0 = fminf(fmaxf(o0, 0.0f), 1.0f);
            o1 = fminf(fmaxf(o1, 0.0f), 1.0f);
            *reinterpret_cast<float2*>(&out[gi]) = make_float2(o0, o1);
        }
    }
}

extern "C" void kernel_launch(void* const* d_in, const int* in_sizes, int n_in,
                              void* d_out, int out_size, void* d_ws, size_t ws_size,
                              hipStream_t stream)
{
    const float* grid    = (const float*)d_in[0];
    const float* noise   = (const float*)d_in[1];
    const float* filters = (const float*)d_in[2];
    const float* w0      = (const float*)d_in[3];
    const float* w1      = (const float*)d_in[4];
    float* out = (float*)d_out;
    float* K   = (float*)d_ws;   // 576 floats

    nca_prep<<<1, 576, 0, stream>>>(filters, w0, w1, K);

    dim3 g(W_ / TW, H_ / TH, B_);
    nca_main<<<g, 256, 0, stream>>>(grid, noise, K, out);
}

// Round 3
// 192.288 us; speedup vs baseline: 1.0072x; 1.0072x over previous
//
#include <hip/hip_runtime.h>

// NCA step collapsed: y = single 8->8 channel 3x3 circular conv with folded
// kernel K[c][c'][3][3] = sum_f (w1@w0)[c,c',f] * filters[f].
// out = clamp(grid + (noise<0.5) * conv(grid,K), 0, 1)
//
// v3: v1 structure (single staging phase, scalar LDS reads, scalar stores)
// with TH=8 tile -> 21.1 KB LDS -> 7 blocks/CU -> ~28 waves/CU for
// latency hiding. Each thread: 2 rows x 1 col x 8 output channels.

#define B_ 16
#define C_ 8
#define H_ 512
#define W_ 512
#define HID_ 32
#define F_ 5

#define TH 8
#define TW 64
#define PER_CH ((TH + 2) * (TW + 2))   // 660
#define TOTAL_ (C_ * PER_CH)           // 5280

// ---- prep: fold w1 @ w0 @ filters into K[8][8][9] ----
__global__ void nca_prep(const float* __restrict__ filters,  // [5][3][3]
                         const float* __restrict__ w0,       // [32][40]
                         const float* __restrict__ w1,       // [8][32]
                         float* __restrict__ K)              // [8][8][9]
{
    int idx = blockIdx.x * blockDim.x + threadIdx.x;
    if (idx >= C_ * C_ * 9) return;
    int k  = idx % 9;
    int t  = idx / 9;
    int cp = t % C_;   // input channel
    int c  = t / C_;   // output channel
    float acc = 0.f;
    #pragma unroll
    for (int f = 0; f < F_; ++f) {
        float we = 0.f;
        for (int o = 0; o < HID_; ++o)
            we += w1[c * HID_ + o] * w0[o * (C_ * F_) + cp * F_ + f];
        acc += we * filters[f * 9 + k];
    }
    K[idx] = acc;
}

__global__ __launch_bounds__(256) void nca_main(
    const float* __restrict__ grid,
    const float* __restrict__ noise,
    const float* __restrict__ K,      // [8][8][9]
    float* __restrict__ out)
{
    __shared__ float lds[C_][TH + 2][TW + 2];   // 8*10*66*4 = 21120 B

    const int b   = blockIdx.z;
    const int h0  = blockIdx.y * TH;
    const int w0c = blockIdx.x * TW;
    const int tid = threadIdx.x;

    // stage all 8 channels with 1-px circular halo (single phase: all
    // global loads issued in one window, max latency overlap)
    for (int i = tid; i < TOTAL_; i += 256) {
        int c   = i / PER_CH;
        int rem = i - c * PER_CH;
        int r   = rem / (TW + 2);
        int col = rem - r * (TW + 2);
        int gh  = (h0 + r - 1) & (H_ - 1);
        int gw  = (w0c + col - 1) & (W_ - 1);
        (&lds[0][0][0])[i] = grid[(((b << 3) + c) << 18) + (gh << 9) + gw];
    }
    __syncthreads();

    const int lw = tid & 63;           // column in tile
    const int R0 = (tid >> 6) << 1;    // 0,2,4,6 -> base row of 2-row strip

    float acc[C_][2];
    #pragma unroll
    for (int c = 0; c < C_; ++c) {
        acc[c][0] = 0.f; acc[c][1] = 0.f;
    }

    #pragma unroll
    for (int cp = 0; cp < C_; ++cp) {
        float v[4][3];
        #pragma unroll
        for (int r = 0; r < 4; ++r)
            #pragma unroll
            for (int cc = 0; cc < 3; ++cc)
                v[r][cc] = lds[cp][R0 + r][lw + cc];

        #pragma unroll
        for (int c = 0; c < C_; ++c) {
            const float* __restrict__ kk = K + (c * C_ + cp) * 9;
            #pragma unroll
            for (int kh = 0; kh < 3; ++kh) {
                #pragma unroll
                for (int kw = 0; kw < 3; ++kw) {
                    const float kv = kk[kh * 3 + kw];
                    acc[c][0] += kv * v[kh + 0][kw];
                    acc[c][1] += kv * v[kh + 1][kw];
                }
            }
        }
    }

    // epilogue: mask, residual, clamp, coalesced scalar store
    #pragma unroll
    for (int c = 0; c < C_; ++c) {
        #pragma unroll
        for (int pr = 0; pr < 2; ++pr) {
            const int h  = h0 + R0 + pr;
            const int gi = (((b << 3) + c) << 18) + (h << 9) + (w0c + lw);
            const float g = lds[c][R0 + 1 + pr][lw + 1];
            const float m = noise[gi];
            float o = (m < 0.5f) ? (g + acc[c][pr]) : g;
            o = fminf(fmaxf(o, 0.0f), 1.0f);
            out[gi] = o;
        }
    }
}

extern "C" void kernel_launch(void* const* d_in, const int* in_sizes, int n_in,
                              void* d_out, int out_size, void* d_ws, size_t ws_size,
                              hipStream_t stream)
{
    const float* grid    = (const float*)d_in[0];
    const float* noise   = (const float*)d_in[1];
    const float* filters = (const float*)d_in[2];
    const float* w0      = (const float*)d_in[3];
    const float* w1      = (const float*)d_in[4];
    float* out = (float*)d_out;
    float* K   = (float*)d_ws;   // 576 floats

    nca_prep<<<1, 576, 0, stream>>>(filters, w0, w1, K);

    dim3 g(W_ / TW, H_ / TH, B_);
    nca_main<<<g, 256, 0, stream>>>(grid, noise, K, out);
}